// Round 2
// baseline (1198.315 us; speedup 1.0000x reference)
//
#include <hip/hip_runtime.h>
#include <hip/hip_fp16.h>
#include <stdint.h>

// SNNClassifier: B=16384, F=256, H=256, C=10, T=100
// Phase 1: layer-1 LIF spike bitmask into d_ws (100 x 16384 x 256 bits).
// Phase 2: persistent-state fused kernel, int8 fused-digit GEMM:
//   W*2^14 = a*64 + b (i8 digits); h = (sum a*(64z) + b*z)*2^-14 via
//   mfma_i32_16x16x64_i8, single exact i32 accumulator.
//
// R10 (R9 failed: __builtin_amdgcn_writelane not exposed on this ROCm ->
// spike_gen reverts to the proven 3-level select tree. Kept from R9, both
// previously unbenched):
//  1. Packed-FP32 LIF (v_pk_add/mul/fma_f32 via float2 ext-vectors) in BOTH
//     kernels. Per-half IEEE == scalar; contract(off) pins the mul-then-add
//     rounding the scalar __fmul_rn/__fadd_rn code had. h = pk_fma(cvt(acc),
//     2^-14, bias) stays exact (pow2-scaled product).  ~11 -> ~8 ops/el.
//  2. K s-loop fully unrolled: (s&1)/(s&2) hw-selects fold to compile time,
//     LDS offsets become immediates. launch_bounds(256,4) caps regalloc.
// Integer acc + identical FP order => absmax must stay EXACTLY 0.003417969.

#define BB 16384
#define FF 256
#define HH 256
#define CC 10
#define TT 100

typedef __attribute__((ext_vector_type(4))) int int4v;
typedef __attribute__((ext_vector_type(2))) float f32x2;

// ---------------- kernel 1: layer-1 spike bitmask ----------------
// Wave owns TWO b: 8 states/thread as 4 float2 pairs. Ballot words
// distributed to lanes 0..7 via 3-level select tree; lanes 0..7 store
// 8 u64 = 64B contiguous per t.
__global__ __launch_bounds__(256) void spike_gen(
    const float* __restrict__ x, unsigned long long* __restrict__ Z) {
#pragma clang fp contract(off)
  const int lane = threadIdx.x & 63;
  const int wv   = threadIdx.x >> 6;
  const int b0   = blockIdx.x * 8 + wv * 2;
  const float K_VM = (float)(0.001 * 100.0);        // 0.1f, numpy-exact
  const float K_ID = (float)(1.0 - 0.001 * 200.0);  // 0.8f, numpy-exact
  const f32x2 kvm2 = {K_VM, K_VM};
  const f32x2 kid2 = {K_ID, K_ID};

  // pair pr <-> states idx=2pr,2pr+1 (idx = jb*4+js; jb=idx>>2, js=idx&3)
  f32x2 v[4], cur[4], xv[4];
#pragma unroll
  for (int pr = 0; pr < 4; ++pr) {
    const int idx0 = 2 * pr, idx1 = 2 * pr + 1;
    const int jb0 = idx0 >> 2, js0 = idx0 & 3;
    const int jb1 = idx1 >> 2, js1 = idx1 & 3;
    xv[pr].x = x[(size_t)(b0 + jb0) * FF + js0 * 64 + lane];
    xv[pr].y = x[(size_t)(b0 + jb1) * FF + js1 * 64 + lane];
    v[pr].x = 0.f; v[pr].y = 0.f;
    cur[pr].x = 0.f; cur[pr].y = 0.f;
  }

  const bool s0 = (lane & 1) != 0, s1 = (lane & 2) != 0, s2 = (lane & 4) != 0;
  unsigned long long* zp = Z + (size_t)b0 * 4;

  for (int t = 0; t < TT; ++t) {
    unsigned long long bal[8];
#pragma unroll
    for (int pr = 0; pr < 4; ++pr) {
      f32x2 vv = v[pr], ci = cur[pr];
      f32x2 d    = ci - vv;          // == (-v)+i bitwise
      f32x2 vd   = vv + kvm2 * d;    // contract off: pk_mul + pk_add
      f32x2 idec = ci * kid2;
      bool zx = vd.x > 1.0f;
      bool zy = vd.y > 1.0f;
      bal[2 * pr]     = __ballot(zx);
      bal[2 * pr + 1] = __ballot(zy);
      v[pr].x = zx ? 0.0f : vd.x;
      v[pr].y = zy ? 0.0f : vd.y;
      cur[pr] = idec + xv[pr];
    }
    // 3-level select tree: lane idx (0..7) picks bal[idx]
    // bal index = jb*4+js ordering matches idx0/idx1 mapping above:
    // bal[k] holds states idx=k (k = 2pr (+1)) = original jb*4+js index.
    unsigned long long m0 = s0 ? bal[1] : bal[0];
    unsigned long long m1 = s0 ? bal[3] : bal[2];
    unsigned long long m2 = s0 ? bal[5] : bal[4];
    unsigned long long m3 = s0 ? bal[7] : bal[6];
    unsigned long long n0 = s1 ? m1 : m0;
    unsigned long long n1 = s1 ? m3 : m2;
    unsigned long long m  = s2 ? n1 : n0;
    if (lane < 8) zp[(size_t)t * (BB * 4) + lane] = m;
  }
}

// ---------------- kernel 2: fused temporal loop (i8) ----------------
// grid: 1024 blocks = 256 bc x 4 hc (hc = bx&3 -> hc-adjacent blocks share
// Z rows in L2). block = 256 thr = 4 waves = 4 b-subtiles of 16 rows; all
// waves share one 64-h chunk (nt=4). 2 t-planes per group (j=2).
// LDS slab 32KB: 32 blocks of 1024B, index (nt*2+d)*4+s, content byte
// [lane*16+i] = digit d of W[h0+nt*16+(lane&15)][s*64+(lane>>4)*16+i].
__global__ __launch_bounds__(256, 4) void snn_main(
    const uint32_t* __restrict__ Z, const float* __restrict__ Wh,
    const float* __restrict__ bh, const float* __restrict__ Wr,
    const float* __restrict__ br, float* __restrict__ out) {
#pragma clang fp contract(off)
  __shared__ __align__(16) char WS[32768];

  const int tid = threadIdx.x;
  const int bx  = blockIdx.x;
  const int hc  = bx & 3;
  const int bc  = bx >> 2;
  const int h0  = hc * 64;
  const int b0  = bc * 64;

  // ---- stage W -> LDS as i8 digit pair, MFMA-fragment order ----
  {
    int4v* ws4 = (int4v*)WS;
#pragma unroll
    for (int half = 0; half < 4; ++half) {
      const int u  = tid + half * 256;
      const int rr = u >> 4;
      const int q  = u & 15;
      const int s  = q >> 2, kq = q & 3;
      const int nt = rr >> 4, n = rr & 15;
      const float* wp = Wh + (size_t)(h0 + rr) * FF + s * 64 + kq * 16;
      uint32_t pa[4], pb[4];
#pragma unroll
      for (int c4 = 0; c4 < 4; ++c4) {
        float4 w4 = *(const float4*)(wp + c4 * 4);
        float wf[4] = {w4.x, w4.y, w4.z, w4.w};
        uint32_t ua = 0, ub = 0;
#pragma unroll
        for (int e = 0; e < 4; ++e) {
          float af = rintf(wf[e] * 256.0f);
          af = fminf(fmaxf(af, -127.0f), 127.0f);
          float bf = rintf(__builtin_fmaf(af, -64.0f, wf[e] * 16384.0f));
          bf = fminf(fmaxf(bf, -127.0f), 127.0f);
          ua |= ((uint32_t)((int)af) & 255u) << (8 * e);
          ub |= ((uint32_t)((int)bf) & 255u) << (8 * e);
        }
        pa[c4] = ua; pb[c4] = ub;
      }
      ws4[((nt * 2 + 0) * 4 + s) * 64 + kq * 16 + n] = *(int4v*)pa;
      ws4[((nt * 2 + 1) * 4 + s) * 64 + kq * 16 + n] = *(int4v*)pb;
    }
  }
  __syncthreads();

  const int lane = tid & 63;
  const int bsub = tid >> 6;
  const int col  = lane & 15;
  const int quad = lane >> 4;
  const bool qhi = (quad & 2) != 0;
  const uint32_t shl16 = (quad & 1) * 16;

  const int brow = b0 + bsub * 16 + col;

  const float K_VM = (float)(0.001 * 100.0);
  const float K_ID = (float)(1.0 - 0.001 * 200.0);
  const f32x2 kvm2 = {K_VM, K_VM};
  const f32x2 kid2 = {K_ID, K_ID};
  const f32x2 hs2  = {6.103515625e-05f, 6.103515625e-05f};

  f32x2 v2[4][2], ii2[4][2];
  uint32_t sc[4];  // packed: byte r of sc[nt] = spike count (<=100)
#pragma unroll
  for (int nt = 0; nt < 4; ++nt) {
    sc[nt] = 0u;
#pragma unroll
    for (int p = 0; p < 2; ++p) {
      v2[nt][p].x = 0.f; v2[nt][p].y = 0.f;
      ii2[nt][p].x = 0.f; ii2[nt][p].y = 0.f;
    }
  }

  f32x2 bias2[4];
#pragma unroll
  for (int nt = 0; nt < 4; ++nt) {
    float b = bh[h0 + nt * 16 + col];
    bias2[nt].x = b; bias2[nt].y = b;
  }

  // per-lane compacted spike halfwords for 2 t-planes
  uint32_t hwS0[2], hwS1[2], hwS2[2], hwS3[2];
  const uint32_t* zrow = Z + (size_t)brow * 8;

  auto load_hw = [&](int tgi) {
#pragma unroll
    for (int j = 0; j < 2; ++j) {
      const uint32_t* p = zrow + ((size_t)tgi * 2 + j) * (size_t)(BB * 8);
      uint4 a = *(const uint4*)p;
      uint4 b4 = *(const uint4*)(p + 4);
      hwS0[j] = (qhi ? a.y : a.x) >> shl16;
      hwS1[j] = (qhi ? a.w : a.z) >> shl16;
      hwS2[j] = (qhi ? b4.y : b4.x) >> shl16;
      hwS3[j] = (qhi ? b4.w : b4.z) >> shl16;
    }
  };
  load_hw(0);

  const char* wsl = WS + lane * 16;
  const int4v* bp = (const int4v*)wsl;

#pragma unroll 1
  for (int tg = 0; tg < TT / 2; ++tg) {
    int4v acc[2][4];
#pragma unroll
    for (int j = 0; j < 2; ++j)
#pragma unroll
      for (int nt = 0; nt < 4; ++nt)
        acc[j][nt] = (int4v){0, 0, 0, 0};

    // ---- K loop: 4 steps of 64 f-columns, both digits fused ----
    // Fully unrolled: (s&1)/(s&2) selects fold, LDS offsets are immediates.
#pragma unroll
    for (int s = 0; s < 4; ++s) {
      int4v Ba[4], Bb[4];
#pragma unroll
      for (int nt = 0; nt < 4; ++nt) {
        Ba[nt] = bp[s * 64 + (nt * 2 + 0) * 256];  // imm offset
        Bb[nt] = bp[s * 64 + (nt * 2 + 1) * 256];
      }
#pragma unroll
      for (int j = 0; j < 2; ++j) {
        uint32_t t0 = (s & 1) ? hwS1[j] : hwS0[j];   // compile-time select
        uint32_t t1 = (s & 1) ? hwS3[j] : hwS2[j];
        uint32_t h16 = (s & 2) ? t1 : t0;
        int4v za, zb_;
#pragma unroll
        for (int p = 0; p < 4; ++p) {
          uint32_t nib = (h16 >> (4 * p)) & 15u;
          uint32_t zbyte = __umul24(nib, 0x204081u) & 0x01010101u;
          zb_[p] = (int)zbyte;
          za[p]  = (int)(zbyte << 6);  // 64*z, fits i8
        }
#pragma unroll
        for (int nt = 0; nt < 4; ++nt) {
          acc[j][nt] = __builtin_amdgcn_mfma_i32_16x16x64_i8(
              za, Ba[nt], acc[j][nt], 0, 0, 0);
          acc[j][nt] = __builtin_amdgcn_mfma_i32_16x16x64_i8(
              zb_, Bb[nt], acc[j][nt], 0, 0, 0);
        }
      }
    }

    // ---- prefetch next tg's spike bits (covered by LIF VALU) ----
    if (tg < TT / 2 - 1) load_hw(tg + 1);

    // ---- 2 sequential layer-2 LIF updates (numpy op order, packed f32) ----
    // h = pk_fma(cvt(acc), 2^-14, bias): product exact -> bit-identical to
    // the two-rounding form. pk halves are IEEE-identical to scalar ops.
#pragma unroll
    for (int j = 0; j < 2; ++j) {
#pragma unroll
      for (int nt = 0; nt < 4; ++nt) {
#pragma unroll
        for (int p = 0; p < 2; ++p) {
          f32x2 hf;
          hf.x = (float)acc[j][nt][2 * p];
          hf.y = (float)acc[j][nt][2 * p + 1];
          f32x2 h = __builtin_elementwise_fma(hf, hs2, bias2[nt]);
          f32x2 vv = v2[nt][p], ci = ii2[nt][p];
          f32x2 d    = ci - vv;         // == (-v)+i bitwise
          f32x2 vd   = vv + kvm2 * d;   // contract off: pk_mul + pk_add
          f32x2 idec = ci * kid2;
          bool zx = vd.x > 1.0f, zy = vd.y > 1.0f;
          v2[nt][p].x = zx ? 0.0f : vd.x;
          v2[nt][p].y = zy ? 0.0f : vd.y;
          ii2[nt][p] = idec + h;
          sc[nt] += ((zx ? 1u : 0u) << (8 * (2 * p))) |
                    ((zy ? 1u : 0u) << (8 * (2 * p + 1)));
        }
      }
    }
  }

  // ---- epilogue: readout GEMM, fused ----
  float mean[4][4];
#pragma unroll
  for (int nt = 0; nt < 4; ++nt)
#pragma unroll
    for (int r = 0; r < 4; ++r)
      mean[nt][r] = __fdiv_rn((float)((sc[nt] >> (8 * r)) & 255u), 100.0f);

#pragma unroll 1
  for (int c = 0; c < CC; ++c) {
    float wc[4];
#pragma unroll
    for (int nt = 0; nt < 4; ++nt) wc[nt] = Wr[c * HH + h0 + nt * 16 + col];
#pragma unroll
    for (int r = 0; r < 4; ++r) {
      float s = 0.f;
#pragma unroll
      for (int nt = 0; nt < 4; ++nt) s = fmaf(mean[nt][r], wc[nt], s);
      s += __shfl_xor(s, 1);
      s += __shfl_xor(s, 2);
      s += __shfl_xor(s, 4);
      s += __shfl_xor(s, 8);
      if (col == 0) {
        int b = b0 + bsub * 16 + quad * 4 + r;
        float add = s + ((hc == 0) ? br[c] : 0.0f);
        atomicAdd(&out[b * CC + c], add);
      }
    }
  }
}

extern "C" void kernel_launch(void* const* d_in, const int* in_sizes, int n_in,
                              void* d_out, int out_size, void* d_ws, size_t ws_size,
                              hipStream_t stream) {
  const float* x  = (const float*)d_in[0];
  const float* Wh = (const float*)d_in[1];
  const float* bh = (const float*)d_in[2];
  const float* Wr = (const float*)d_in[3];
  const float* br = (const float*)d_in[4];
  float* out = (float*)d_out;

  // workspace: spike bitmask, 100*16384*32B = 52.4 MB
  unsigned long long* Z = (unsigned long long*)d_ws;

  hipMemsetAsync(d_out, 0, (size_t)out_size * sizeof(float), stream);
  spike_gen<<<BB / 8, 256, 0, stream>>>(x, Z);
  snn_main<<<1024, 256, 0, stream>>>((const uint32_t*)Z, Wh, bh, Wr, br, out);
}

// Round 3
// 404.585 us; speedup vs baseline: 2.9618x; 2.9618x over previous
//
#include <hip/hip_runtime.h>
#include <hip/hip_fp16.h>
#include <stdint.h>

// SNNClassifier: B=16384, F=256, H=256, C=10, T=100
// Phase 1: layer-1 LIF spike bitmask into d_ws (100 x 16384 x 256 bits).
// Phase 2: persistent-state fused kernel, int8 fused-digit GEMM:
//   W*2^14 = a*64 + b (i8 digits); h = (sum a*(64z) + b*z)*2^-14 via
//   mfma_i32_16x16x64_i8, single exact i32 accumulator.
//
// R11 (post-mortem R10: full s-unroll spilled -> FETCH 102MB->3.56GB of
// scratch traffic, snn_main 277->1045us. Revert to R8 structure EXACTLY
// -- rolled s-loop, R8 scalar spike_gen -- keep ONE change isolated):
//  * Packed-FP32 layer-2 LIF (v_pk_sub/mul/add/fma_f32 via float2
//    ext-vectors, contract(off) pins pk_mul+pk_add order). Per-half IEEE
//    == scalar __fmul_rn/__fadd_rn sequence; h = pk_fma(cvt(acc), 2^-14,
//    bias) exact (pow2-scaled product < 2^22). ~11 -> ~8 ops/element on
//    the block that is ~63% of snn_main's VALU issue.
// Integer acc + identical FP order => absmax must stay EXACTLY 0.003417969.

#define BB 16384
#define FF 256
#define HH 256
#define CC 10
#define TT 100

typedef __attribute__((ext_vector_type(4))) int int4v;
typedef __attribute__((ext_vector_type(2))) float f32x2;

// ---------------- kernel 1: layer-1 spike bitmask ----------------
// Wave owns TWO b: 8 states/thread (jb<2 x js<4). Lanes 0..7 store 8 u64
// = 64B contiguous per t. (R8-proven version, untouched.)
__global__ __launch_bounds__(256) void spike_gen(
    const float* __restrict__ x, unsigned long long* __restrict__ Z) {
  const int lane = threadIdx.x & 63;
  const int wv   = threadIdx.x >> 6;
  const int b0   = blockIdx.x * 8 + wv * 2;
  const float K_VM = (float)(0.001 * 100.0);        // 0.1f, numpy-exact
  const float K_ID = (float)(1.0 - 0.001 * 200.0);  // 0.8f, numpy-exact

  float v[8], cur[8], xv[8];
#pragma unroll
  for (int jb = 0; jb < 2; ++jb)
#pragma unroll
    for (int js = 0; js < 4; ++js) {
      const int idx = jb * 4 + js;
      xv[idx] = x[(size_t)(b0 + jb) * FF + js * 64 + lane];
      v[idx] = 0.0f; cur[idx] = 0.0f;
    }

  const bool s0 = (lane & 1) != 0, s1 = (lane & 2) != 0, s2 = (lane & 4) != 0;
  unsigned long long* zp = Z + (size_t)b0 * 4;

  for (int t = 0; t < TT; ++t) {
    unsigned long long bal[8];
#pragma unroll
    for (int idx = 0; idx < 8; ++idx) {
      float vd   = __fadd_rn(v[idx], __fmul_rn(K_VM, __fadd_rn(-v[idx], cur[idx])));
      float idec = __fmul_rn(cur[idx], K_ID);
      bool z = (vd > 1.0f);
      bal[idx] = __ballot(z);
      v[idx]   = z ? 0.0f : vd;
      cur[idx] = __fadd_rn(idec, xv[idx]);
    }
    // 3-level select tree: lane idx (0..7) picks bal[idx]
    unsigned long long m0 = s0 ? bal[1] : bal[0];
    unsigned long long m1 = s0 ? bal[3] : bal[2];
    unsigned long long m2 = s0 ? bal[5] : bal[4];
    unsigned long long m3 = s0 ? bal[7] : bal[6];
    unsigned long long n0 = s1 ? m1 : m0;
    unsigned long long n1 = s1 ? m3 : m2;
    unsigned long long m  = s2 ? n1 : n0;
    if (lane < 8) zp[(size_t)t * (BB * 4) + lane] = m;
  }
}

// ---------------- kernel 2: fused temporal loop (i8) ----------------
// grid: 1024 blocks = 256 bc x 4 hc (hc = bx&3 -> hc-adjacent blocks share
// Z rows in L2). block = 256 thr = 4 waves = 4 b-subtiles of 16 rows; all
// waves share one 64-h chunk (nt=4). 2 t-planes per group (j=2).
// LDS slab 32KB: 32 blocks of 1024B, index (nt*2+d)*4+s, content byte
// [lane*16+i] = digit d of W[h0+nt*16+(lane&15)][s*64+(lane>>4)*16+i].
__global__ __launch_bounds__(256, 4) void snn_main(
    const uint32_t* __restrict__ Z, const float* __restrict__ Wh,
    const float* __restrict__ bh, const float* __restrict__ Wr,
    const float* __restrict__ br, float* __restrict__ out) {
#pragma clang fp contract(off)
  __shared__ __align__(16) char WS[32768];

  const int tid = threadIdx.x;
  const int bx  = blockIdx.x;
  const int hc  = bx & 3;
  const int bc  = bx >> 2;
  const int h0  = hc * 64;
  const int b0  = bc * 64;

  // ---- stage W -> LDS as i8 digit pair, MFMA-fragment order ----
  // 1024 units: u = rr*16 + s*4 + kq (rr<64); each writes 16B per digit.
  {
    int4v* ws4 = (int4v*)WS;
#pragma unroll
    for (int half = 0; half < 4; ++half) {
      const int u  = tid + half * 256;
      const int rr = u >> 4;
      const int q  = u & 15;
      const int s  = q >> 2, kq = q & 3;
      const int nt = rr >> 4, n = rr & 15;
      const float* wp = Wh + (size_t)(h0 + rr) * FF + s * 64 + kq * 16;
      uint32_t pa[4], pb[4];
#pragma unroll
      for (int c4 = 0; c4 < 4; ++c4) {
        float4 w4 = *(const float4*)(wp + c4 * 4);
        float wf[4] = {w4.x, w4.y, w4.z, w4.w};
        uint32_t ua = 0, ub = 0;
#pragma unroll
        for (int e = 0; e < 4; ++e) {
          float af = rintf(wf[e] * 256.0f);
          af = fminf(fmaxf(af, -127.0f), 127.0f);
          float bf = rintf(__builtin_fmaf(af, -64.0f, wf[e] * 16384.0f));
          bf = fminf(fmaxf(bf, -127.0f), 127.0f);
          ua |= ((uint32_t)((int)af) & 255u) << (8 * e);
          ub |= ((uint32_t)((int)bf) & 255u) << (8 * e);
        }
        pa[c4] = ua; pb[c4] = ub;
      }
      ws4[((nt * 2 + 0) * 4 + s) * 64 + kq * 16 + n] = *(int4v*)pa;
      ws4[((nt * 2 + 1) * 4 + s) * 64 + kq * 16 + n] = *(int4v*)pb;
    }
  }
  __syncthreads();

  const int lane = tid & 63;
  const int bsub = tid >> 6;
  const int col  = lane & 15;
  const int quad = lane >> 4;
  const bool qhi = (quad & 2) != 0;
  const uint32_t shl16 = (quad & 1) * 16;

  const int brow = b0 + bsub * 16 + col;

  const float K_VM = (float)(0.001 * 100.0);
  const float K_ID = (float)(1.0 - 0.001 * 200.0);
  const f32x2 kvm2 = {K_VM, K_VM};
  const f32x2 kid2 = {K_ID, K_ID};
  const f32x2 hs2  = {6.103515625e-05f, 6.103515625e-05f};

  f32x2 v2[4][2], ii2[4][2];
  uint32_t sc[4];  // packed: byte r of sc[nt] = spike count (<=100)
#pragma unroll
  for (int nt = 0; nt < 4; ++nt) {
    sc[nt] = 0u;
#pragma unroll
    for (int p = 0; p < 2; ++p) {
      v2[nt][p].x = 0.f; v2[nt][p].y = 0.f;
      ii2[nt][p].x = 0.f; ii2[nt][p].y = 0.f;
    }
  }

  f32x2 bias2[4];
#pragma unroll
  for (int nt = 0; nt < 4; ++nt) {
    float b = bh[h0 + nt * 16 + col];
    bias2[nt].x = b; bias2[nt].y = b;
  }

  // per-lane compacted spike halfwords for 2 t-planes
  uint32_t hwS0[2], hwS1[2], hwS2[2], hwS3[2];
  const uint32_t* zrow = Z + (size_t)brow * 8;

  auto load_hw = [&](int tgi) {
#pragma unroll
    for (int j = 0; j < 2; ++j) {
      const uint32_t* p = zrow + ((size_t)tgi * 2 + j) * (size_t)(BB * 8);
      uint4 a = *(const uint4*)p;
      uint4 b4 = *(const uint4*)(p + 4);
      hwS0[j] = (qhi ? a.y : a.x) >> shl16;
      hwS1[j] = (qhi ? a.w : a.z) >> shl16;
      hwS2[j] = (qhi ? b4.y : b4.x) >> shl16;
      hwS3[j] = (qhi ? b4.w : b4.z) >> shl16;
    }
  };
  load_hw(0);

  const char* wsl = WS + lane * 16;

#pragma unroll 1
  for (int tg = 0; tg < TT / 2; ++tg) {
    int4v acc[2][4];
#pragma unroll
    for (int j = 0; j < 2; ++j)
#pragma unroll
      for (int nt = 0; nt < 4; ++nt)
        acc[j][nt] = (int4v){0, 0, 0, 0};

    // ---- K loop: 4 steps of 64 f-columns, both digits fused ----
    // ROLLED (unroll 1): R10's full unroll spilled to scratch.
#pragma unroll 1
    for (int s = 0; s < 4; ++s) {
      const int4v* bp = (const int4v*)(wsl + s * 1024);
      int4v Ba[4], Bb[4];
#pragma unroll
      for (int nt = 0; nt < 4; ++nt) {
        Ba[nt] = bp[(nt * 2 + 0) * 256];  // imm offset (nt*2+d)*4096 B
        Bb[nt] = bp[(nt * 2 + 1) * 256];
      }
#pragma unroll
      for (int j = 0; j < 2; ++j) {
        uint32_t t0 = (s & 1) ? hwS1[j] : hwS0[j];
        uint32_t t1 = (s & 1) ? hwS3[j] : hwS2[j];
        uint32_t h16 = (s & 2) ? t1 : t0;
        int4v za, zb_;
#pragma unroll
        for (int p = 0; p < 4; ++p) {
          uint32_t nib = (h16 >> (4 * p)) & 15u;
          uint32_t zbyte = __umul24(nib, 0x204081u) & 0x01010101u;
          zb_[p] = (int)zbyte;
          za[p]  = (int)(zbyte << 6);  // 64*z, fits i8
        }
#pragma unroll
        for (int nt = 0; nt < 4; ++nt) {
          acc[j][nt] = __builtin_amdgcn_mfma_i32_16x16x64_i8(
              za, Ba[nt], acc[j][nt], 0, 0, 0);
          acc[j][nt] = __builtin_amdgcn_mfma_i32_16x16x64_i8(
              zb_, Bb[nt], acc[j][nt], 0, 0, 0);
        }
      }
    }

    // ---- prefetch next tg's spike bits (covered by LIF VALU) ----
    if (tg < TT / 2 - 1) load_hw(tg + 1);

    // ---- 2 sequential layer-2 LIF updates (numpy op order, packed f32) ----
    // h = pk_fma(cvt(acc), 2^-14, bias): product exact -> bit-identical to
    // the two-rounding form. pk halves are IEEE-identical to scalar ops;
    // contract(off) pins the pk_mul+pk_add rounding order.
#pragma unroll
    for (int j = 0; j < 2; ++j) {
#pragma unroll
      for (int nt = 0; nt < 4; ++nt) {
#pragma unroll
        for (int p = 0; p < 2; ++p) {
          f32x2 hf;
          hf.x = (float)acc[j][nt][2 * p];
          hf.y = (float)acc[j][nt][2 * p + 1];
          f32x2 h = __builtin_elementwise_fma(hf, hs2, bias2[nt]);
          f32x2 vv = v2[nt][p], ci = ii2[nt][p];
          f32x2 d    = ci - vv;         // == (-v)+i bitwise
          f32x2 vd   = vv + kvm2 * d;   // pk_mul then pk_add
          f32x2 idec = ci * kid2;
          bool zx = vd.x > 1.0f, zy = vd.y > 1.0f;
          v2[nt][p].x = zx ? 0.0f : vd.x;
          v2[nt][p].y = zy ? 0.0f : vd.y;
          ii2[nt][p] = idec + h;
          sc[nt] += ((zx ? 1u : 0u) << (8 * (2 * p))) |
                    ((zy ? 1u : 0u) << (8 * (2 * p + 1)));
        }
      }
    }
  }

  // ---- epilogue: readout GEMM, fused ----
  float mean[4][4];
#pragma unroll
  for (int nt = 0; nt < 4; ++nt)
#pragma unroll
    for (int r = 0; r < 4; ++r)
      mean[nt][r] = __fdiv_rn((float)((sc[nt] >> (8 * r)) & 255u), 100.0f);

#pragma unroll 1
  for (int c = 0; c < CC; ++c) {
    float wc[4];
#pragma unroll
    for (int nt = 0; nt < 4; ++nt) wc[nt] = Wr[c * HH + h0 + nt * 16 + col];
#pragma unroll
    for (int r = 0; r < 4; ++r) {
      float s = 0.f;
#pragma unroll
      for (int nt = 0; nt < 4; ++nt) s = fmaf(mean[nt][r], wc[nt], s);
      s += __shfl_xor(s, 1);
      s += __shfl_xor(s, 2);
      s += __shfl_xor(s, 4);
      s += __shfl_xor(s, 8);
      if (col == 0) {
        int b = b0 + bsub * 16 + quad * 4 + r;
        float add = s + ((hc == 0) ? br[c] : 0.0f);
        atomicAdd(&out[b * CC + c], add);
      }
    }
  }
}

extern "C" void kernel_launch(void* const* d_in, const int* in_sizes, int n_in,
                              void* d_out, int out_size, void* d_ws, size_t ws_size,
                              hipStream_t stream) {
  const float* x  = (const float*)d_in[0];
  const float* Wh = (const float*)d_in[1];
  const float* bh = (const float*)d_in[2];
  const float* Wr = (const float*)d_in[3];
  const float* br = (const float*)d_in[4];
  float* out = (float*)d_out;

  // workspace: spike bitmask, 100*16384*32B = 52.4 MB
  unsigned long long* Z = (unsigned long long*)d_ws;

  hipMemsetAsync(d_out, 0, (size_t)out_size * sizeof(float), stream);
  spike_gen<<<BB / 8, 256, 0, stream>>>(x, Z);
  snn_main<<<1024, 256, 0, stream>>>((const uint32_t*)Z, Wh, bh, Wr, br, out);
}

// Round 5
// 391.521 us; speedup vs baseline: 3.0607x; 1.0334x over previous
//
#include <hip/hip_runtime.h>
#include <hip/hip_fp16.h>
#include <stdint.h>

// SNNClassifier: B=16384, F=256, H=256, C=10, T=100
// Phase 1: layer-1 LIF spike bitmask into d_ws (100 x 16384 x 256 bits).
// Phase 2: persistent-state fused kernel, int8 fused-digit GEMM:
//   W*2^14 = a*64 + b (i8 digits); h = (sum a*(64z) + b*z)*2^-14 via
//   mfma_i32_16x16x64_i8, single exact i32 accumulator.
//
// R13 (post-mortem R12: inline-asm v_writelane read ballot SGPRs written
// by compiler v_cmp -> unpatched VALU->SGPR read hazard -> stale bits,
// absmax 2e-2. Lane ops on VALU-written SGPRs via raw asm are BANNED;
// spike_gen reverted to the R8-proven select tree EXACTLY. Kept, now
// isolated for a clean A/B read):
//  * snn_main: per s-step, unpack BOTH j t-planes between the 8 ds_reads
//    and the MFMAs -> 2x lgkm latency cover + clean 16-MFMA burst
//    (cross-wave VALU/MFMA overlap). Integer-exact reorder. +8 VGPR.
// Integer acc + identical FP order => absmax must stay EXACTLY 0.003417969.

#define BB 16384
#define FF 256
#define HH 256
#define CC 10
#define TT 100

typedef __attribute__((ext_vector_type(4))) int int4v;

// ---------------- kernel 1: layer-1 spike bitmask ----------------
// Wave owns TWO b: 8 states/thread (jb<2 x js<4). Lanes 0..7 store 8 u64
// = 64B contiguous per t. (R8-proven version, untouched.)
__global__ __launch_bounds__(256) void spike_gen(
    const float* __restrict__ x, unsigned long long* __restrict__ Z) {
  const int lane = threadIdx.x & 63;
  const int wv   = threadIdx.x >> 6;
  const int b0   = blockIdx.x * 8 + wv * 2;
  const float K_VM = (float)(0.001 * 100.0);        // 0.1f, numpy-exact
  const float K_ID = (float)(1.0 - 0.001 * 200.0);  // 0.8f, numpy-exact

  float v[8], cur[8], xv[8];
#pragma unroll
  for (int jb = 0; jb < 2; ++jb)
#pragma unroll
    for (int js = 0; js < 4; ++js) {
      const int idx = jb * 4 + js;
      xv[idx] = x[(size_t)(b0 + jb) * FF + js * 64 + lane];
      v[idx] = 0.0f; cur[idx] = 0.0f;
    }

  const bool s0 = (lane & 1) != 0, s1 = (lane & 2) != 0, s2 = (lane & 4) != 0;
  unsigned long long* zp = Z + (size_t)b0 * 4;

  for (int t = 0; t < TT; ++t) {
    unsigned long long bal[8];
#pragma unroll
    for (int idx = 0; idx < 8; ++idx) {
      float vd   = __fadd_rn(v[idx], __fmul_rn(K_VM, __fadd_rn(-v[idx], cur[idx])));
      float idec = __fmul_rn(cur[idx], K_ID);
      bool z = (vd > 1.0f);
      bal[idx] = __ballot(z);
      v[idx]   = z ? 0.0f : vd;
      cur[idx] = __fadd_rn(idec, xv[idx]);
    }
    // 3-level select tree: lane idx (0..7) picks bal[idx]
    unsigned long long m0 = s0 ? bal[1] : bal[0];
    unsigned long long m1 = s0 ? bal[3] : bal[2];
    unsigned long long m2 = s0 ? bal[5] : bal[4];
    unsigned long long m3 = s0 ? bal[7] : bal[6];
    unsigned long long n0 = s1 ? m1 : m0;
    unsigned long long n1 = s1 ? m3 : m2;
    unsigned long long m  = s2 ? n1 : n0;
    if (lane < 8) zp[(size_t)t * (BB * 4) + lane] = m;
  }
}

// ---------------- kernel 2: fused temporal loop (i8) ----------------
// grid: 1024 blocks = 256 bc x 4 hc (hc = bx&3 -> hc-adjacent blocks share
// Z rows in L2). block = 256 thr = 4 waves = 4 b-subtiles of 16 rows; all
// waves share one 64-h chunk (nt=4). 2 t-planes per group (j=2).
// LDS slab 32KB: 32 blocks of 1024B, index (nt*2+d)*4+s, content byte
// [lane*16+i] = digit d of W[h0+nt*16+(lane&15)][s*64+(lane>>4)*16+i].
__global__ __launch_bounds__(256, 4) void snn_main(
    const uint32_t* __restrict__ Z, const float* __restrict__ Wh,
    const float* __restrict__ bh, const float* __restrict__ Wr,
    const float* __restrict__ br, float* __restrict__ out) {
  __shared__ __align__(16) char WS[32768];

  const int tid = threadIdx.x;
  const int bx  = blockIdx.x;
  const int hc  = bx & 3;
  const int bc  = bx >> 2;
  const int h0  = hc * 64;
  const int b0  = bc * 64;

  // ---- stage W -> LDS as i8 digit pair, MFMA-fragment order ----
  // 1024 units: u = rr*16 + s*4 + kq (rr<64); each writes 16B per digit.
  {
    int4v* ws4 = (int4v*)WS;
#pragma unroll
    for (int half = 0; half < 4; ++half) {
      const int u  = tid + half * 256;
      const int rr = u >> 4;
      const int q  = u & 15;
      const int s  = q >> 2, kq = q & 3;
      const int nt = rr >> 4, n = rr & 15;
      const float* wp = Wh + (size_t)(h0 + rr) * FF + s * 64 + kq * 16;
      uint32_t pa[4], pb[4];
#pragma unroll
      for (int c4 = 0; c4 < 4; ++c4) {
        float4 w4 = *(const float4*)(wp + c4 * 4);
        float wf[4] = {w4.x, w4.y, w4.z, w4.w};
        uint32_t ua = 0, ub = 0;
#pragma unroll
        for (int e = 0; e < 4; ++e) {
          float af = rintf(wf[e] * 256.0f);
          af = fminf(fmaxf(af, -127.0f), 127.0f);
          float bf = rintf(__builtin_fmaf(af, -64.0f, wf[e] * 16384.0f));
          bf = fminf(fmaxf(bf, -127.0f), 127.0f);
          ua |= ((uint32_t)((int)af) & 255u) << (8 * e);
          ub |= ((uint32_t)((int)bf) & 255u) << (8 * e);
        }
        pa[c4] = ua; pb[c4] = ub;
      }
      ws4[((nt * 2 + 0) * 4 + s) * 64 + kq * 16 + n] = *(int4v*)pa;
      ws4[((nt * 2 + 1) * 4 + s) * 64 + kq * 16 + n] = *(int4v*)pb;
    }
  }
  __syncthreads();

  const int lane = tid & 63;
  const int bsub = tid >> 6;
  const int col  = lane & 15;
  const int quad = lane >> 4;
  const bool qhi = (quad & 2) != 0;
  const uint32_t shl16 = (quad & 1) * 16;

  const int brow = b0 + bsub * 16 + col;

  const float K_VM = (float)(0.001 * 100.0);
  const float K_ID = (float)(1.0 - 0.001 * 200.0);

  float v2[4][4], ii[4][4];
  uint32_t sc[4];  // packed: byte r of sc[nt] = spike count (<=100)
#pragma unroll
  for (int nt = 0; nt < 4; ++nt) {
    sc[nt] = 0u;
#pragma unroll
    for (int r = 0; r < 4; ++r) { v2[nt][r] = 0.f; ii[nt][r] = 0.f; }
  }

  float bias[4];
#pragma unroll
  for (int nt = 0; nt < 4; ++nt) bias[nt] = bh[h0 + nt * 16 + col];

  // per-lane compacted spike halfwords for 2 t-planes
  uint32_t hwS0[2], hwS1[2], hwS2[2], hwS3[2];
  const uint32_t* zrow = Z + (size_t)brow * 8;

  auto load_hw = [&](int tgi) {
#pragma unroll
    for (int j = 0; j < 2; ++j) {
      const uint32_t* p = zrow + ((size_t)tgi * 2 + j) * (size_t)(BB * 8);
      uint4 a = *(const uint4*)p;
      uint4 b4 = *(const uint4*)(p + 4);
      hwS0[j] = (qhi ? a.y : a.x) >> shl16;
      hwS1[j] = (qhi ? a.w : a.z) >> shl16;
      hwS2[j] = (qhi ? b4.y : b4.x) >> shl16;
      hwS3[j] = (qhi ? b4.w : b4.z) >> shl16;
    }
  };
  load_hw(0);

  const char* wsl = WS + lane * 16;

#pragma unroll 1
  for (int tg = 0; tg < TT / 2; ++tg) {
    int4v acc[2][4];
#pragma unroll
    for (int j = 0; j < 2; ++j)
#pragma unroll
      for (int nt = 0; nt < 4; ++nt)
        acc[j][nt] = (int4v){0, 0, 0, 0};

    // ---- K loop: 4 steps of 64 f-columns, both digits fused ----
    // ROLLED (unroll 1): R10's full unroll spilled to scratch.
    // Order per s: issue 8 ds_reads -> unpack BOTH j (covers lgkm
    // latency) -> 16-MFMA burst.
#pragma unroll 1
    for (int s = 0; s < 4; ++s) {
      const int4v* bp = (const int4v*)(wsl + s * 1024);
      int4v Ba[4], Bb[4];
#pragma unroll
      for (int nt = 0; nt < 4; ++nt) {
        Ba[nt] = bp[(nt * 2 + 0) * 256];  // imm offset (nt*2+d)*4096 B
        Bb[nt] = bp[(nt * 2 + 1) * 256];
      }
      int4v za[2], zb_[2];
#pragma unroll
      for (int j = 0; j < 2; ++j) {
        uint32_t t0 = (s & 1) ? hwS1[j] : hwS0[j];
        uint32_t t1 = (s & 1) ? hwS3[j] : hwS2[j];
        uint32_t h16 = (s & 2) ? t1 : t0;
#pragma unroll
        for (int p = 0; p < 4; ++p) {
          uint32_t nib = (h16 >> (4 * p)) & 15u;
          uint32_t zbyte = __umul24(nib, 0x204081u) & 0x01010101u;
          zb_[j][p] = (int)zbyte;
          za[j][p]  = (int)(zbyte << 6);  // 64*z, fits i8
        }
      }
#pragma unroll
      for (int j = 0; j < 2; ++j)
#pragma unroll
        for (int nt = 0; nt < 4; ++nt) {
          acc[j][nt] = __builtin_amdgcn_mfma_i32_16x16x64_i8(
              za[j], Ba[nt], acc[j][nt], 0, 0, 0);
          acc[j][nt] = __builtin_amdgcn_mfma_i32_16x16x64_i8(
              zb_[j], Bb[nt], acc[j][nt], 0, 0, 0);
        }
    }

    // ---- prefetch next tg's spike bits (covered by LIF VALU) ----
    if (tg < TT / 2 - 1) load_hw(tg + 1);

    // ---- 2 sequential layer-2 LIF updates (numpy op order) ----
    // h = fma(cvt(acc), 2^-14, bias): product exact -> bit-identical to
    // the two-rounding form.
#pragma unroll
    for (int j = 0; j < 2; ++j) {
#pragma unroll
      for (int nt = 0; nt < 4; ++nt) {
#pragma unroll
        for (int r = 0; r < 4; ++r) {
          float h  = __builtin_fmaf((float)acc[j][nt][r], 6.103515625e-05f,
                                    bias[nt]);
          float vv = v2[nt][r], ci = ii[nt][r];
          float vd   = __fadd_rn(vv, __fmul_rn(K_VM, __fadd_rn(-vv, ci)));
          float idec = __fmul_rn(ci, K_ID);
          bool z = (vd > 1.0f);
          v2[nt][r] = z ? 0.0f : vd;
          ii[nt][r] = __fadd_rn(idec, h);
          sc[nt] += (z ? 1u : 0u) << (8 * r);
        }
      }
    }
  }

  // ---- epilogue: readout GEMM, fused ----
  float mean[4][4];
#pragma unroll
  for (int nt = 0; nt < 4; ++nt)
#pragma unroll
    for (int r = 0; r < 4; ++r)
      mean[nt][r] = __fdiv_rn((float)((sc[nt] >> (8 * r)) & 255u), 100.0f);

#pragma unroll 1
  for (int c = 0; c < CC; ++c) {
    float wc[4];
#pragma unroll
    for (int nt = 0; nt < 4; ++nt) wc[nt] = Wr[c * HH + h0 + nt * 16 + col];
#pragma unroll
    for (int r = 0; r < 4; ++r) {
      float s = 0.f;
#pragma unroll
      for (int nt = 0; nt < 4; ++nt) s = fmaf(mean[nt][r], wc[nt], s);
      s += __shfl_xor(s, 1);
      s += __shfl_xor(s, 2);
      s += __shfl_xor(s, 4);
      s += __shfl_xor(s, 8);
      if (col == 0) {
        int b = b0 + bsub * 16 + quad * 4 + r;
        float add = s + ((hc == 0) ? br[c] : 0.0f);
        atomicAdd(&out[b * CC + c], add);
      }
    }
  }
}

extern "C" void kernel_launch(void* const* d_in, const int* in_sizes, int n_in,
                              void* d_out, int out_size, void* d_ws, size_t ws_size,
                              hipStream_t stream) {
  const float* x  = (const float*)d_in[0];
  const float* Wh = (const float*)d_in[1];
  const float* bh = (const float*)d_in[2];
  const float* Wr = (const float*)d_in[3];
  const float* br = (const float*)d_in[4];
  float* out = (float*)d_out;

  // workspace: spike bitmask, 100*16384*32B = 52.4 MB
  unsigned long long* Z = (unsigned long long*)d_ws;

  hipMemsetAsync(d_out, 0, (size_t)out_size * sizeof(float), stream);
  spike_gen<<<BB / 8, 256, 0, stream>>>(x, Z);
  snn_main<<<1024, 256, 0, stream>>>((const uint32_t*)Z, Wh, bh, Wr, br, out);
}